// Round 3
// baseline (3597.414 us; speedup 1.0000x reference)
//
#include <hip/hip_runtime.h>
#include <cstdint>

#define NN 100000
#define NE 3200000
#define DD 128

#define NB 782      // ceil(NN/128) node bins
#define NBP 800     // padded bin count for LDS arrays
#define T3 6400     // edges per scatter tile (NE/6400 = 500 tiles)
#define EPT 25      // edges per thread in scatter (6400/256)

// ---------------- K1: bin histogram ----------------
__global__ __launch_bounds__(256) void hist_k(
    const int* __restrict__ rows, int* __restrict__ hist)
{
    int base = blockIdx.x * 1024 + threadIdx.x;
    #pragma unroll
    for (int i = 0; i < 4; ++i)
        atomicAdd(&hist[rows[base + i * 256] >> 7], 1);
}

// ---------------- K2: exclusive scan over bins ----------------
__global__ __launch_bounds__(1024) void scan_k(
    const int* __restrict__ hist, int* __restrict__ bin_off,
    int* __restrict__ bin_cursor)
{
    __shared__ int sd[1024];
    int t = threadIdx.x;
    int v = (t < NB) ? hist[t] : 0;
    sd[t] = v; __syncthreads();
    for (int off = 1; off < 1024; off <<= 1) {
        int add = (t >= off) ? sd[t - off] : 0;
        __syncthreads();
        sd[t] += add;
        __syncthreads();
    }
    if (t < NB) {
        int excl = sd[t] - v;
        bin_off[t] = excl;
        bin_cursor[t] = excl;
    }
}

// ---------------- K3: tile counting-sort scatter (coalesced writes) --------
// Record: x = col | (r_local << 17)  (col<2^17, r_local<128), y = weight bits
__global__ __launch_bounds__(256) void tile_scatter_k(
    const int* __restrict__ rows, const int* __restrict__ cols,
    const float* __restrict__ ew, int* __restrict__ bin_cursor,
    uint2* __restrict__ bucket)
{
    __shared__ int h[NBP];     // tile hist / counts
    __shared__ int toff[NBP];  // in-tile exclusive offsets
    __shared__ int pos[NBP];   // running fill cursor
    __shared__ int gb[NBP];    // global base per bin
    __shared__ int ps[256];    // per-thread partial sums for block scan
    __shared__ uint2 rec[T3];  // reordered tile records (50 KB)

    int t = threadIdx.x;
    long base = (long)blockIdx.x * T3;

    for (int b = t; b < NBP; b += 256) h[b] = 0;
    __syncthreads();

    int rv[EPT];
    #pragma unroll
    for (int i = 0; i < EPT; ++i) {
        int e = base + i * 256 + t;
        rv[i] = rows[e];
        atomicAdd(&h[rv[i] >> 7], 1);
    }
    __syncthreads();

    // block scan: thread t owns bins [4t, 4t+4)
    int c[4]; int s0 = 0;
    #pragma unroll
    for (int j = 0; j < 4; ++j) {
        int b = 4 * t + j;
        c[j] = (b < NBP) ? h[b] : 0;
        s0 += c[j];
    }
    ps[t] = s0; __syncthreads();
    for (int off = 1; off < 256; off <<= 1) {
        int add = (t >= off) ? ps[t - off] : 0;
        __syncthreads();
        ps[t] += add;
        __syncthreads();
    }
    int excl = ps[t] - s0;
    #pragma unroll
    for (int j = 0; j < 4; ++j) {
        int b = 4 * t + j;
        if (b < NBP) { toff[b] = excl; pos[b] = excl; excl += c[j]; }
    }
    __syncthreads();

    // reserve global ranges
    for (int b = t; b < NB; b += 256)
        gb[b] = atomicAdd(&bin_cursor[b], h[b]);
    __syncthreads();

    // reorder records into LDS
    #pragma unroll
    for (int i = 0; i < EPT; ++i) {
        int e = base + i * 256 + t;
        int r = rv[i];
        int b = r >> 7;
        int slot = atomicAdd(&pos[b], 1);
        uint2 rr;
        rr.x = (unsigned)cols[e] | ((unsigned)(r & 127) << 17);
        rr.y = __float_as_uint(ew[e]);
        rec[slot] = rr;
    }
    __syncthreads();

    // wave-cooperative copy-out: each bin's run written by one wave
    int wid = t >> 6, lane = t & 63;
    for (int b = wid; b < NB; b += 4) {
        int cnt = h[b];
        if (!cnt) continue;
        int src = toff[b], dst = gb[b];
        for (int i = lane; i < cnt; i += 64)
            bucket[dst + i] = rec[src + i];
    }
}

// ---------------- K4: bin gather with LDS accumulation ----------------
__global__ __launch_bounds__(512) void bin_gather_k(
    const float* __restrict__ x, const uint2* __restrict__ bucket,
    const int* __restrict__ bin_off, const int* __restrict__ hist,
    float* __restrict__ agg)
{
    __shared__ float ag[128][DD];   // 64 KB accumulator tile

    int t = threadIdx.x, b = blockIdx.x;
    int wid = t >> 6, lane = t & 63;

    float4* az = (float4*)&ag[0][0];
    for (int i = t; i < 128 * DD / 4; i += 512)
        az[i] = make_float4(0.f, 0.f, 0.f, 0.f);
    __syncthreads();

    int start = bin_off[b], cnt = hist[b];
    int end = start + cnt;
    const float2* x2 = reinterpret_cast<const float2*>(x);

    // 4-deep pipelined, wave-strided over the bin's records
    for (int i = start + wid; i < end; i += 32) {
        int j1 = i + 8, j2 = i + 16, j3 = i + 24;
        uint2 r0 = bucket[i];
        uint2 r1 = (j1 < end) ? bucket[j1] : make_uint2(0u, 0u);
        uint2 r2 = (j2 < end) ? bucket[j2] : make_uint2(0u, 0u);
        uint2 r3 = (j3 < end) ? bucket[j3] : make_uint2(0u, 0u);
        float2 v0 = x2[(size_t)(r0.x & 0x1FFFF) * 64 + lane];
        float2 v1 = x2[(size_t)(r1.x & 0x1FFFF) * 64 + lane];
        float2 v2 = x2[(size_t)(r2.x & 0x1FFFF) * 64 + lane];
        float2 v3 = x2[(size_t)(r3.x & 0x1FFFF) * 64 + lane];
        float w0 = __uint_as_float(r0.y);
        float w1 = __uint_as_float(r1.y);
        float w2 = __uint_as_float(r2.y);
        float w3 = __uint_as_float(r3.y);
        int a0 = (r0.x >> 17) & 127, a1 = (r1.x >> 17) & 127;
        int a2 = (r2.x >> 17) & 127, a3 = (r3.x >> 17) & 127;
        unsafeAtomicAdd(&ag[a0][2 * lane],     w0 * v0.x);
        unsafeAtomicAdd(&ag[a0][2 * lane + 1], w0 * v0.y);
        unsafeAtomicAdd(&ag[a1][2 * lane],     w1 * v1.x);
        unsafeAtomicAdd(&ag[a1][2 * lane + 1], w1 * v1.y);
        unsafeAtomicAdd(&ag[a2][2 * lane],     w2 * v2.x);
        unsafeAtomicAdd(&ag[a2][2 * lane + 1], w2 * v2.y);
        unsafeAtomicAdd(&ag[a3][2 * lane],     w3 * v3.x);
        unsafeAtomicAdd(&ag[a3][2 * lane + 1], w3 * v3.y);
    }
    __syncthreads();

    // coalesced write-out of the bin's node rows
    int node0 = b * 128;
    int nrow = (NN - node0 < 128) ? (NN - node0) : 128;
    float4* og = (float4*)(agg + (size_t)node0 * DD);
    for (int i = t; i < nrow * (DD / 4); i += 512)
        og[i] = az[i];
}

// ---------------- fallback scatter (ws too small) ----------------
__global__ __launch_bounds__(256) void scatter_k(
    const float* __restrict__ x, const float* __restrict__ ew,
    const int* __restrict__ rows, const int* __restrict__ cols,
    float* __restrict__ agg)
{
    int e    = blockIdx.x * 4 + (threadIdx.x >> 6);
    int lane = threadIdx.x & 63;
    int r = rows[e];
    int c = cols[e];
    float w = ew[e];
    float2 v = reinterpret_cast<const float2*>(x + (size_t)c * DD)[lane];
    float* ag = agg + (size_t)r * DD + lane * 2;
    atomicAdd(ag,     w * v.x);
    atomicAdd(ag + 1, w * v.y);
}

// ---------------- K5: GEMM + tanh (in-place, unchanged) ----------------
__global__ __launch_bounds__(256) void gemm_tanh_k(
    const float* __restrict__ agg, const float* __restrict__ W,
    float* __restrict__ out)
{
    __shared__ float Wt[DD][DD + 4];
    __shared__ float At[32][DD];

    int tid = threadIdx.x;
    for (int i = tid; i < DD * DD; i += 256) {
        int o = i >> 7, k = i & 127;
        Wt[k][o] = W[i];
    }
    int row0 = blockIdx.x * 32;
    for (int i = tid; i < 32 * DD; i += 256) {
        At[i >> 7][i & 127] = agg[(size_t)row0 * DD + i];
    }
    __syncthreads();

    int colg = tid & 31;
    int rowg = tid >> 5;
    int c0 = colg * 4;
    int r0 = rowg * 4;

    float acc[4][4] = {};
    for (int k = 0; k < DD; ++k) {
        float4 wv = *reinterpret_cast<const float4*>(&Wt[k][c0]);
        #pragma unroll
        for (int i = 0; i < 4; ++i) {
            float a = At[r0 + i][k];
            acc[i][0] += a * wv.x;
            acc[i][1] += a * wv.y;
            acc[i][2] += a * wv.z;
            acc[i][3] += a * wv.w;
        }
    }

    #pragma unroll
    for (int i = 0; i < 4; ++i) {
        int r = row0 + r0 + i;
        float4 o4 = { tanhf(acc[i][0]), tanhf(acc[i][1]),
                      tanhf(acc[i][2]), tanhf(acc[i][3]) };
        *reinterpret_cast<float4*>(&out[(size_t)r * DD + c0]) = o4;
    }
}

extern "C" void kernel_launch(void* const* d_in, const int* in_sizes, int n_in,
                              void* d_out, int out_size, void* d_ws, size_t ws_size,
                              hipStream_t stream) {
    const float* x  = (const float*)d_in[0];
    const float* W  = (const float*)d_in[1];
    const float* ew = (const float*)d_in[2];
    const int*   ei = (const int*)d_in[3];
    const int* rows = ei;
    const int* cols = ei + NE;
    float* out = (float*)d_out;   // doubles as agg buffer

    // Workspace: hist[NB] | bin_off[NB] | bin_cursor[NB] | pad | bucket[NE]
    size_t hdr = ((size_t)3 * NB + 16) & ~(size_t)15;   // 16-aligned int count
    size_t need = hdr * sizeof(int) + (size_t)NE * sizeof(uint2);

    if (ws_size >= need) {
        int* hist       = (int*)d_ws;
        int* bin_off    = hist + NB;
        int* bin_cursor = bin_off + NB;
        uint2* bucket   = (uint2*)((int*)d_ws + hdr);

        hipMemsetAsync(hist, 0, (size_t)NB * sizeof(int), stream);
        hist_k<<<NE / 1024, 256, 0, stream>>>(rows, hist);
        scan_k<<<1, 1024, 0, stream>>>(hist, bin_off, bin_cursor);
        tile_scatter_k<<<NE / T3, 256, 0, stream>>>(rows, cols, ew, bin_cursor, bucket);
        bin_gather_k<<<NB, 512, 0, stream>>>(x, bucket, bin_off, hist, out);
    } else {
        hipMemsetAsync(out, 0, (size_t)NN * DD * sizeof(float), stream);
        scatter_k<<<NE / 4, 256, 0, stream>>>(x, ew, rows, cols, out);
    }
    gemm_tanh_k<<<NN / 32, 256, 0, stream>>>(out, W, out);
}

// Round 4
// 449.346 us; speedup vs baseline: 8.0059x; 8.0059x over previous
//
#include <hip/hip_runtime.h>
#include <cstdint>

#define NN 100000
#define NE 3200000
#define DD 128

#define NB 782      // ceil(NN/128) node bins (128 nodes each)
#define NBP 800     // padded bin count for LDS arrays
#define T3 6400     // edges per tile (NE/T3 = 500 tiles)
#define EPT 25      // edges per thread (6400/256)

#define CAP 6144    // max records per bin handled by sort_bin_k (avg 4092, 32 sigma)
#define RPT 24      // CAP/256 register records per thread

// ---------------- K1: bin histogram (LDS pre-aggregated) ----------------
__global__ __launch_bounds__(256) void hist_k(
    const int* __restrict__ rows, int* __restrict__ hist)
{
    __shared__ int lh[NBP];
    int t = threadIdx.x;
    for (int b = t; b < NBP; b += 256) lh[b] = 0;
    __syncthreads();
    int base = blockIdx.x * T3;
    #pragma unroll
    for (int i = 0; i < EPT; ++i)
        atomicAdd(&lh[rows[base + i * 256 + t] >> 7], 1);
    __syncthreads();
    for (int b = t; b < NB; b += 256) {
        int v = lh[b];
        if (v) atomicAdd(&hist[b], v);
    }
}

// ---------------- K2: exclusive scan over bins ----------------
__global__ __launch_bounds__(1024) void scan_k(
    const int* __restrict__ hist, int* __restrict__ bin_off,
    int* __restrict__ bin_cursor)
{
    __shared__ int sd[1024];
    int t = threadIdx.x;
    int v = (t < NB) ? hist[t] : 0;
    sd[t] = v; __syncthreads();
    for (int off = 1; off < 1024; off <<= 1) {
        int add = (t >= off) ? sd[t - off] : 0;
        __syncthreads();
        sd[t] += add;
        __syncthreads();
    }
    if (t < NB) {
        int excl = sd[t] - v;
        bin_off[t] = excl;
        bin_cursor[t] = excl;
    }
}

// ---------------- K3: tile counting-sort scatter (validated r3) ----------
// Record: x = col | (r_local << 17), y = weight bits
__global__ __launch_bounds__(256) void tile_scatter_k(
    const int* __restrict__ rows, const int* __restrict__ cols,
    const float* __restrict__ ew, int* __restrict__ bin_cursor,
    uint2* __restrict__ bucket)
{
    __shared__ int h[NBP];
    __shared__ int toff[NBP];
    __shared__ int pos[NBP];
    __shared__ int gb[NBP];
    __shared__ int ps[256];
    __shared__ uint2 rec[T3];   // 50 KB

    int t = threadIdx.x;
    int base = blockIdx.x * T3;

    for (int b = t; b < NBP; b += 256) h[b] = 0;
    __syncthreads();

    int rv[EPT];
    #pragma unroll
    for (int i = 0; i < EPT; ++i) {
        int e = base + i * 256 + t;
        rv[i] = rows[e];
        atomicAdd(&h[rv[i] >> 7], 1);
    }
    __syncthreads();

    int c[4]; int s0 = 0;
    #pragma unroll
    for (int j = 0; j < 4; ++j) {
        int b = 4 * t + j;
        c[j] = (b < NBP) ? h[b] : 0;
        s0 += c[j];
    }
    ps[t] = s0; __syncthreads();
    for (int off = 1; off < 256; off <<= 1) {
        int add = (t >= off) ? ps[t - off] : 0;
        __syncthreads();
        ps[t] += add;
        __syncthreads();
    }
    int excl = ps[t] - s0;
    #pragma unroll
    for (int j = 0; j < 4; ++j) {
        int b = 4 * t + j;
        if (b < NBP) { toff[b] = excl; pos[b] = excl; excl += c[j]; }
    }
    __syncthreads();

    for (int b = t; b < NB; b += 256)
        gb[b] = atomicAdd(&bin_cursor[b], h[b]);
    __syncthreads();

    #pragma unroll
    for (int i = 0; i < EPT; ++i) {
        int e = base + i * 256 + t;
        int r = rv[i];
        int b = r >> 7;
        int slot = atomicAdd(&pos[b], 1);
        uint2 rr;
        rr.x = (unsigned)cols[e] | ((unsigned)(r & 127) << 17);
        rr.y = __float_as_uint(ew[e]);
        rec[slot] = rr;
    }
    __syncthreads();

    int wid = t >> 6, lane = t & 63;
    for (int b = wid; b < NB; b += 4) {
        int cnt = h[b];
        if (!cnt) continue;
        int src = toff[b], dst = gb[b];
        for (int i = lane; i < cnt; i += 64)
            bucket[dst + i] = rec[src + i];
    }
}

// ---------------- K4: per-bin node-granular counting sort (in-place) -----
__global__ __launch_bounds__(256) void sort_bin_k(
    const int* __restrict__ bin_off, const int* __restrict__ hist,
    uint2* __restrict__ bucket,
    int* __restrict__ node_off, int* __restrict__ node_cnt)
{
    __shared__ uint2 rec[CAP];      // 48 KB sorted destination
    __shared__ int lh[128], sc[128], lpos[128];

    int b = blockIdx.x, t = threadIdx.x;
    int start = bin_off[b];
    int cnt = hist[b];
    if (cnt > CAP) cnt = CAP;   // safety clamp; statistically impossible here

    // load records to registers, statically indexed (no scratch)
    uint2 mr[RPT];
    #pragma unroll
    for (int j = 0; j < RPT; ++j) {
        int idx = t + j * 256;
        mr[j] = (idx < cnt) ? bucket[start + idx] : make_uint2(0u, 0u);
    }

    if (t < 128) lh[t] = 0;
    __syncthreads();
    #pragma unroll
    for (int j = 0; j < RPT; ++j) {
        int idx = t + j * 256;
        if (idx < cnt) atomicAdd(&lh[(mr[j].x >> 17) & 127], 1);
    }
    __syncthreads();

    // exclusive scan over 128 local nodes (all threads hit barriers)
    int v = (t < 128) ? lh[t] : 0;
    if (t < 128) sc[t] = v;
    __syncthreads();
    for (int off = 1; off < 128; off <<= 1) {
        int add = (t >= off && t < 128) ? sc[t - off] : 0;
        __syncthreads();
        if (t < 128) sc[t] += add;
        __syncthreads();
    }
    if (t < 128) {
        int excl = sc[t] - v;
        lpos[t] = excl;
        int node = b * 128 + t;
        if (node < NN) {
            node_off[node] = start + excl;
            node_cnt[node] = v;
        }
    }
    __syncthreads();

    // reorder registers -> LDS
    #pragma unroll
    for (int j = 0; j < RPT; ++j) {
        int idx = t + j * 256;
        if (idx < cnt) {
            int slot = atomicAdd(&lpos[(mr[j].x >> 17) & 127], 1);
            rec[slot] = mr[j];
        }
    }
    __syncthreads();

    // coalesced write-back (in-place; block owns this range exclusively)
    for (int i = t; i < cnt; i += 256)
        bucket[start + i] = rec[i];
}

// ---------------- K5: per-node gather (validated r2) ----------------
__global__ __launch_bounds__(256) void gather_k(
    const float* __restrict__ x, const uint2* __restrict__ bucket,
    const int* __restrict__ node_off, const int* __restrict__ node_cnt,
    float* __restrict__ agg)
{
    int node = blockIdx.x * 4 + (threadIdx.x >> 6);   // NN % 4 == 0
    int lane = threadIdx.x & 63;
    int start = node_off[node];
    int cnt   = node_cnt[node];
    const float2* x2 = reinterpret_cast<const float2*>(x);

    float2 acc = {0.f, 0.f};
    int i = 0;
    for (; i + 1 < cnt; i += 2) {
        uint2 e0 = bucket[start + i];
        uint2 e1 = bucket[start + i + 1];
        float2 v0 = x2[(size_t)(e0.x & 0x1FFFF) * 64 + lane];
        float2 v1 = x2[(size_t)(e1.x & 0x1FFFF) * 64 + lane];
        float w0 = __uint_as_float(e0.y);
        float w1 = __uint_as_float(e1.y);
        acc.x += w0 * v0.x;
        acc.y += w0 * v0.y;
        acc.x += w1 * v1.x;
        acc.y += w1 * v1.y;
    }
    if (i < cnt) {
        uint2 e0 = bucket[start + i];
        float2 v0 = x2[(size_t)(e0.x & 0x1FFFF) * 64 + lane];
        float w0 = __uint_as_float(e0.y);
        acc.x += w0 * v0.x;
        acc.y += w0 * v0.y;
    }
    reinterpret_cast<float2*>(agg + (size_t)node * DD)[lane] = acc;
}

// ---------------- fallback scatter (ws too small) ----------------
__global__ __launch_bounds__(256) void scatter_k(
    const float* __restrict__ x, const float* __restrict__ ew,
    const int* __restrict__ rows, const int* __restrict__ cols,
    float* __restrict__ agg)
{
    int e    = blockIdx.x * 4 + (threadIdx.x >> 6);
    int lane = threadIdx.x & 63;
    int r = rows[e];
    int c = cols[e];
    float w = ew[e];
    float2 v = reinterpret_cast<const float2*>(x + (size_t)c * DD)[lane];
    float* ag = agg + (size_t)r * DD + lane * 2;
    atomicAdd(ag,     w * v.x);
    atomicAdd(ag + 1, w * v.y);
}

// ---------------- K6: GEMM + tanh (in-place, validated r1) ----------------
__global__ __launch_bounds__(256) void gemm_tanh_k(
    const float* __restrict__ agg, const float* __restrict__ W,
    float* __restrict__ out)
{
    __shared__ float Wt[DD][DD + 4];
    __shared__ float At[32][DD];

    int tid = threadIdx.x;
    for (int i = tid; i < DD * DD; i += 256) {
        int o = i >> 7, k = i & 127;
        Wt[k][o] = W[i];
    }
    int row0 = blockIdx.x * 32;
    for (int i = tid; i < 32 * DD; i += 256) {
        At[i >> 7][i & 127] = agg[(size_t)row0 * DD + i];
    }
    __syncthreads();

    int colg = tid & 31;
    int rowg = tid >> 5;
    int c0 = colg * 4;
    int r0 = rowg * 4;

    float acc[4][4] = {};
    for (int k = 0; k < DD; ++k) {
        float4 wv = *reinterpret_cast<const float4*>(&Wt[k][c0]);
        #pragma unroll
        for (int i = 0; i < 4; ++i) {
            float a = At[r0 + i][k];
            acc[i][0] += a * wv.x;
            acc[i][1] += a * wv.y;
            acc[i][2] += a * wv.z;
            acc[i][3] += a * wv.w;
        }
    }

    #pragma unroll
    for (int i = 0; i < 4; ++i) {
        int r = row0 + r0 + i;
        float4 o4 = { tanhf(acc[i][0]), tanhf(acc[i][1]),
                      tanhf(acc[i][2]), tanhf(acc[i][3]) };
        *reinterpret_cast<float4*>(&out[(size_t)r * DD + c0]) = o4;
    }
}

extern "C" void kernel_launch(void* const* d_in, const int* in_sizes, int n_in,
                              void* d_out, int out_size, void* d_ws, size_t ws_size,
                              hipStream_t stream) {
    const float* x  = (const float*)d_in[0];
    const float* W  = (const float*)d_in[1];
    const float* ew = (const float*)d_in[2];
    const int*   ei = (const int*)d_in[3];
    const int* rows = ei;
    const int* cols = ei + NE;
    float* out = (float*)d_out;   // doubles as agg buffer

    // Workspace: hist[NB] | bin_off[NB] | bin_cursor[NB] | node_off[NN] |
    //            node_cnt[NN] | pad | bucket[NE] (uint2)
    size_t ints = (size_t)3 * NB + (size_t)2 * NN;
    size_t hdr = (ints + 3) & ~(size_t)3;            // 16B-align bucket
    size_t need = hdr * sizeof(int) + (size_t)NE * sizeof(uint2);

    if (ws_size >= need) {
        int* hist       = (int*)d_ws;
        int* bin_off    = hist + NB;
        int* bin_cursor = bin_off + NB;
        int* node_off   = bin_cursor + NB;
        int* node_cnt   = node_off + NN;
        uint2* bucket   = (uint2*)((int*)d_ws + hdr);

        hipMemsetAsync(hist, 0, (size_t)NB * sizeof(int), stream);
        hist_k<<<NE / T3, 256, 0, stream>>>(rows, hist);
        scan_k<<<1, 1024, 0, stream>>>(hist, bin_off, bin_cursor);
        tile_scatter_k<<<NE / T3, 256, 0, stream>>>(rows, cols, ew, bin_cursor, bucket);
        sort_bin_k<<<NB, 256, 0, stream>>>(bin_off, hist, bucket, node_off, node_cnt);
        gather_k<<<NN / 4, 256, 0, stream>>>(x, bucket, node_off, node_cnt, out);
    } else {
        hipMemsetAsync(out, 0, (size_t)NN * DD * sizeof(float), stream);
        scatter_k<<<NE / 4, 256, 0, stream>>>(x, ew, rows, cols, out);
    }
    gemm_tanh_k<<<NN / 32, 256, 0, stream>>>(out, W, out);
}

// Round 5
// 365.344 us; speedup vs baseline: 9.8467x; 1.2299x over previous
//
#include <hip/hip_runtime.h>
#include <cstdint>

#define NN 100000
#define NE 3200000
#define DD 128

#define NB 782      // ceil(NN/128) node bins (128 nodes each)
#define NBP 800     // padded bin count for LDS arrays
#define T3 6400     // edges per tile (NE/T3 = 500 tiles)
#define EPT 25      // edges per thread (6400/256)

#define CAP 5120    // max records per bin in sort_bin_k (mean 4092, sigma 64 -> 16 sigma)
#define RPT 20      // CAP/256
#define KEYS 2048   // (r_local 7b << 4) | col_chunk 4b

typedef __attribute__((ext_vector_type(8))) short s8v;   // 8 bf16 (4 VGPR)
typedef __attribute__((ext_vector_type(4))) float f4v;   // 4 f32 acc

__device__ __forceinline__ unsigned f2bf(float f) {       // RNE f32->bf16 bits
    unsigned u = __float_as_uint(f);
    return (u + 0x7fffu + ((u >> 16) & 1u)) >> 16;
}
__device__ __forceinline__ float bf2f(unsigned b) { return __uint_as_float(b << 16); }
__device__ __forceinline__ float tanh_fast(float x) {
    float e = __expf(2.0f * x);           // e^{2x}; inf for large x -> returns 1
    return 1.0f - 2.0f / (e + 1.0f);
}

// ---------------- K1: bin histogram (LDS pre-aggregated) ----------------
__global__ __launch_bounds__(256) void hist_k(
    const int* __restrict__ rows, int* __restrict__ hist)
{
    __shared__ int lh[NBP];
    int t = threadIdx.x;
    for (int b = t; b < NBP; b += 256) lh[b] = 0;
    __syncthreads();
    int base = blockIdx.x * T3;
    #pragma unroll
    for (int i = 0; i < EPT; ++i)
        atomicAdd(&lh[rows[base + i * 256 + t] >> 7], 1);
    __syncthreads();
    for (int b = t; b < NB; b += 256) {
        int v = lh[b];
        if (v) atomicAdd(&hist[b], v);
    }
}

// ---------------- K2: exclusive scan over bins ----------------
__global__ __launch_bounds__(1024) void scan_k(
    const int* __restrict__ hist, int* __restrict__ bin_off,
    int* __restrict__ bin_cursor)
{
    __shared__ int sd[1024];
    int t = threadIdx.x;
    int v = (t < NB) ? hist[t] : 0;
    sd[t] = v; __syncthreads();
    for (int off = 1; off < 1024; off <<= 1) {
        int add = (t >= off) ? sd[t - off] : 0;
        __syncthreads();
        sd[t] += add;
        __syncthreads();
    }
    if (t < NB) {
        int excl = sd[t] - v;
        bin_off[t] = excl;
        bin_cursor[t] = excl;
    }
}

// ---------------- K3: tile counting-sort scatter (validated r3/r4) -------
// Record: x = col | (r_local << 17), y = weight bits
__global__ __launch_bounds__(256) void tile_scatter_k(
    const int* __restrict__ rows, const int* __restrict__ cols,
    const float* __restrict__ ew, int* __restrict__ bin_cursor,
    uint2* __restrict__ bucket)
{
    __shared__ int h[NBP];
    __shared__ int toff[NBP];
    __shared__ int pos[NBP];
    __shared__ int gb[NBP];
    __shared__ int ps[256];
    __shared__ uint2 rec[T3];   // 50 KB

    int t = threadIdx.x;
    int base = blockIdx.x * T3;

    for (int b = t; b < NBP; b += 256) h[b] = 0;
    __syncthreads();

    int rv[EPT];
    #pragma unroll
    for (int i = 0; i < EPT; ++i) {
        int e = base + i * 256 + t;
        rv[i] = rows[e];
        atomicAdd(&h[rv[i] >> 7], 1);
    }
    __syncthreads();

    int c[4]; int s0 = 0;
    #pragma unroll
    for (int j = 0; j < 4; ++j) {
        int b = 4 * t + j;
        c[j] = (b < NBP) ? h[b] : 0;
        s0 += c[j];
    }
    ps[t] = s0; __syncthreads();
    for (int off = 1; off < 256; off <<= 1) {
        int add = (t >= off) ? ps[t - off] : 0;
        __syncthreads();
        ps[t] += add;
        __syncthreads();
    }
    int excl = ps[t] - s0;
    #pragma unroll
    for (int j = 0; j < 4; ++j) {
        int b = 4 * t + j;
        if (b < NBP) { toff[b] = excl; pos[b] = excl; excl += c[j]; }
    }
    __syncthreads();

    for (int b = t; b < NB; b += 256)
        gb[b] = atomicAdd(&bin_cursor[b], h[b]);
    __syncthreads();

    #pragma unroll
    for (int i = 0; i < EPT; ++i) {
        int e = base + i * 256 + t;
        int r = rv[i];
        int b = r >> 7;
        int slot = atomicAdd(&pos[b], 1);
        uint2 rr;
        rr.x = (unsigned)cols[e] | ((unsigned)(r & 127) << 17);
        rr.y = __float_as_uint(ew[e]);
        rec[slot] = rr;
    }
    __syncthreads();

    int wid = t >> 6, lane = t & 63;
    for (int b = wid; b < NB; b += 4) {
        int cnt = h[b];
        if (!cnt) continue;
        int src = toff[b], dst = gb[b];
        for (int i = lane; i < cnt; i += 64)
            bucket[dst + i] = rec[src + i];
    }
}

// ---------------- K4: per-bin sort by (node, col-chunk) -------------------
// key = (r_local << 4) | (col >> 13): node-grouped, col-chunk ascending
// within node -> moving-window L2 locality in the gather.
__global__ __launch_bounds__(256) void sort_bin_k(
    const int* __restrict__ bin_off, const int* __restrict__ hist,
    uint2* __restrict__ bucket,
    int* __restrict__ node_off, int* __restrict__ node_cnt)
{
    __shared__ uint2 rec[CAP];      // 40 KB
    __shared__ int lh[KEYS];        // 8 KB: counts -> exclusive offsets
    __shared__ int lpos[KEYS];      // 8 KB: fill cursors
    __shared__ int ps[256];

    int b = blockIdx.x, t = threadIdx.x;
    int start = bin_off[b];
    int cnt = hist[b];
    if (cnt > CAP) cnt = CAP;   // safety clamp (16 sigma, never expected)

    uint2 mr[RPT];
    #pragma unroll
    for (int j = 0; j < RPT; ++j) {
        int idx = t + j * 256;
        mr[j] = (idx < cnt) ? bucket[start + idx] : make_uint2(0u, 0u);
    }

    for (int k = t; k < KEYS; k += 256) lh[k] = 0;
    __syncthreads();

    #pragma unroll
    for (int j = 0; j < RPT; ++j) {
        int idx = t + j * 256;
        if (idx < cnt) {
            unsigned key = ((mr[j].x >> 17) << 4) | ((mr[j].x & 0x1FFFFu) >> 13);
            atomicAdd(&lh[key], 1);
        }
    }
    __syncthreads();

    // exclusive scan over 2048 keys: thread t owns keys [8t, 8t+8)
    int c8[8]; int s0 = 0;
    #pragma unroll
    for (int j = 0; j < 8; ++j) { c8[j] = lh[8 * t + j]; s0 += c8[j]; }
    ps[t] = s0; __syncthreads();
    for (int off = 1; off < 256; off <<= 1) {
        int add = (t >= off) ? ps[t - off] : 0;
        __syncthreads();
        ps[t] += add;
        __syncthreads();
    }
    int excl = ps[t] - s0;
    #pragma unroll
    for (int j = 0; j < 8; ++j) {
        int k = 8 * t + j;
        int tmp = c8[j];
        lh[k] = excl; lpos[k] = excl;
        excl += tmp;
    }
    __syncthreads();

    // per-node offsets/counts from key boundaries
    if (t < 128) {
        int off0 = lh[t << 4];
        int off1 = (t < 127) ? lh[(t + 1) << 4] : cnt;
        int node = b * 128 + t;
        if (node < NN) {
            node_off[node] = start + off0;
            node_cnt[node] = off1 - off0;
        }
    }
    __syncthreads();

    // reorder registers -> LDS
    #pragma unroll
    for (int j = 0; j < RPT; ++j) {
        int idx = t + j * 256;
        if (idx < cnt) {
            unsigned key = ((mr[j].x >> 17) << 4) | ((mr[j].x & 0x1FFFFu) >> 13);
            int slot = atomicAdd(&lpos[key], 1);
            rec[slot] = mr[j];
        }
    }
    __syncthreads();

    for (int i = t; i < cnt; i += 256)
        bucket[start + i] = rec[i];
}

// ---------------- K5: per-node gather, packed (hi,lo) bf16 output --------
__global__ __launch_bounds__(256) void gather_k(
    const float* __restrict__ x, const uint2* __restrict__ bucket,
    const int* __restrict__ node_off, const int* __restrict__ node_cnt,
    unsigned* __restrict__ aggp)
{
    int node = blockIdx.x * 4 + (threadIdx.x >> 6);   // NN % 4 == 0
    int lane = threadIdx.x & 63;
    int start = node_off[node];
    int end   = start + node_cnt[node];
    const float2* x2 = reinterpret_cast<const float2*>(x);

    float2 acc = {0.f, 0.f};
    int i = start;
    for (; i + 3 < end; i += 4) {
        uint2 e0 = bucket[i],     e1 = bucket[i + 1];
        uint2 e2 = bucket[i + 2], e3 = bucket[i + 3];
        float2 v0 = x2[(size_t)(e0.x & 0x1FFFF) * 64 + lane];
        float2 v1 = x2[(size_t)(e1.x & 0x1FFFF) * 64 + lane];
        float2 v2 = x2[(size_t)(e2.x & 0x1FFFF) * 64 + lane];
        float2 v3 = x2[(size_t)(e3.x & 0x1FFFF) * 64 + lane];
        float w0 = __uint_as_float(e0.y), w1 = __uint_as_float(e1.y);
        float w2 = __uint_as_float(e2.y), w3 = __uint_as_float(e3.y);
        acc.x += w0 * v0.x; acc.y += w0 * v0.y;
        acc.x += w1 * v1.x; acc.y += w1 * v1.y;
        acc.x += w2 * v2.x; acc.y += w2 * v2.y;
        acc.x += w3 * v3.x; acc.y += w3 * v3.y;
    }
    for (; i < end; ++i) {
        uint2 e0 = bucket[i];
        float2 v0 = x2[(size_t)(e0.x & 0x1FFFF) * 64 + lane];
        float w0 = __uint_as_float(e0.y);
        acc.x += w0 * v0.x; acc.y += w0 * v0.y;
    }

    // pack f32 -> (bf16 hi << 16) | bf16 lo(residual)
    unsigned hx = f2bf(acc.x);
    unsigned lx = f2bf(acc.x - bf2f(hx));
    unsigned hy = f2bf(acc.y);
    unsigned ly = f2bf(acc.y - bf2f(hy));
    uint2 o;
    o.x = (hx << 16) | lx;
    o.y = (hy << 16) | ly;
    reinterpret_cast<uint2*>(aggp + (size_t)node * DD)[lane] = o;
}

// ---------------- K6: MFMA GEMM + tanh (bf16 hi/lo split, in-place) ------
// out[n][o] = tanh( sum_k agg[n][k] * W[o][k] ), A=aggp packed, B^T=W.
// Block: 128 rows x 128 cols, 4 waves x (32 rows x 128 cols) = 16 tiles/wave.
__device__ __forceinline__ int wswz(int o, int k) {
    // uint16 element index for W[o][k] with 16B XOR swizzle (G4 fix)
    int byte = (o << 8) + (k << 1);
    byte ^= (o & 7) << 4;
    return byte >> 1;
}
__device__ __forceinline__ void unpack8(uint4 a, uint4 b, s8v& hi, s8v& lo) {
    unsigned u[8] = {a.x, a.y, a.z, a.w, b.x, b.y, b.z, b.w};
    #pragma unroll
    for (int j = 0; j < 8; ++j) {
        hi[j] = (short)(u[j] >> 16);
        lo[j] = (short)(u[j] & 0xffffu);
    }
}

__global__ __launch_bounds__(256) void gemm_mfma_k(
    const unsigned* __restrict__ aggp, const float* __restrict__ W,
    float* __restrict__ out)
{
    __shared__ __align__(16) unsigned short Wh[128 * 128];  // 32 KB
    __shared__ __align__(16) unsigned short Wl[128 * 128];  // 32 KB

    int t = threadIdx.x;
    // stage W split into bf16 hi/lo, swizzled
    for (int i = t; i < 128 * 128; i += 256) {
        int o = i >> 7, k = i & 127;
        float f = W[i];
        unsigned h = f2bf(f);
        unsigned l = f2bf(f - bf2f(h));
        int idx = wswz(o, k);
        Wh[idx] = (unsigned short)h;
        Wl[idx] = (unsigned short)l;
    }
    __syncthreads();

    int lane = t & 63;
    int w    = t >> 6;
    int rbase = blockIdx.x * 128 + w * 32;     // this wave's 32 rows
    int fr = lane & 15, fq = lane >> 4;

    f4v acc[2][8];
    #pragma unroll
    for (int rt = 0; rt < 2; ++rt)
        #pragma unroll
        for (int nt = 0; nt < 8; ++nt)
            acc[rt][nt] = 0.0f;

    #pragma unroll
    for (int ks = 0; ks < 4; ++ks) {
        int kb = ks * 32 + fq * 8;
        // a-frags (2 rowtiles), packed global load + unpack
        s8v ah[2], al[2];
        #pragma unroll
        for (int rt = 0; rt < 2; ++rt) {
            int r = rbase + rt * 16 + fr;
            int rc = (r < NN) ? r : (NN - 1);
            const uint4* p = reinterpret_cast<const uint4*>(aggp + (size_t)rc * DD + kb);
            unpack8(p[0], p[1], ah[rt], al[rt]);
        }
        #pragma unroll
        for (int nt = 0; nt < 8; ++nt) {
            int o = nt * 16 + fr;
            int kk = ks * 32 + fq * 8;
            s8v bh = *reinterpret_cast<const s8v*>(&Wh[wswz(o, kk)]);
            s8v bl = *reinterpret_cast<const s8v*>(&Wl[wswz(o, kk)]);
            #pragma unroll
            for (int rt = 0; rt < 2; ++rt) {
                acc[rt][nt] = __builtin_amdgcn_mfma_f32_16x16x32_bf16(ah[rt], bh, acc[rt][nt], 0, 0, 0);
                acc[rt][nt] = __builtin_amdgcn_mfma_f32_16x16x32_bf16(al[rt], bh, acc[rt][nt], 0, 0, 0);
                acc[rt][nt] = __builtin_amdgcn_mfma_f32_16x16x32_bf16(ah[rt], bl, acc[rt][nt], 0, 0, 0);
            }
        }
    }

    // epilogue: tanh + store (C/D: col = lane&15, row = (lane>>4)*4 + reg)
    #pragma unroll
    for (int rt = 0; rt < 2; ++rt) {
        int rr = rbase + rt * 16 + fq * 4;
        #pragma unroll
        for (int nt = 0; nt < 8; ++nt) {
            int col = nt * 16 + fr;
            #pragma unroll
            for (int j = 0; j < 4; ++j) {
                int row = rr + j;
                if (row < NN)
                    out[(size_t)row * DD + col] = tanh_fast(acc[rt][nt][j]);
            }
        }
    }
}

// ---------------- fallback path (ws too small) ----------------
__global__ __launch_bounds__(256) void scatter_k(
    const float* __restrict__ x, const float* __restrict__ ew,
    const int* __restrict__ rows, const int* __restrict__ cols,
    float* __restrict__ agg)
{
    int e    = blockIdx.x * 4 + (threadIdx.x >> 6);
    int lane = threadIdx.x & 63;
    int r = rows[e];
    int c = cols[e];
    float w = ew[e];
    float2 v = reinterpret_cast<const float2*>(x + (size_t)c * DD)[lane];
    float* ag = agg + (size_t)r * DD + lane * 2;
    atomicAdd(ag,     w * v.x);
    atomicAdd(ag + 1, w * v.y);
}

__global__ __launch_bounds__(256) void gemm_tanh_k(
    const float* __restrict__ agg, const float* __restrict__ W,
    float* __restrict__ out)
{
    __shared__ float Wt[DD][DD + 4];
    __shared__ float At[32][DD];

    int tid = threadIdx.x;
    for (int i = tid; i < DD * DD; i += 256) {
        int o = i >> 7, k = i & 127;
        Wt[k][o] = W[i];
    }
    int row0 = blockIdx.x * 32;
    for (int i = tid; i < 32 * DD; i += 256) {
        At[i >> 7][i & 127] = agg[(size_t)row0 * DD + i];
    }
    __syncthreads();

    int colg = tid & 31;
    int rowg = tid >> 5;
    int c0 = colg * 4;
    int r0 = rowg * 4;

    float acc[4][4] = {};
    for (int k = 0; k < DD; ++k) {
        float4 wv = *reinterpret_cast<const float4*>(&Wt[k][c0]);
        #pragma unroll
        for (int i = 0; i < 4; ++i) {
            float a = At[r0 + i][k];
            acc[i][0] += a * wv.x;
            acc[i][1] += a * wv.y;
            acc[i][2] += a * wv.z;
            acc[i][3] += a * wv.w;
        }
    }

    #pragma unroll
    for (int i = 0; i < 4; ++i) {
        int r = row0 + r0 + i;
        float4 o4 = { tanhf(acc[i][0]), tanhf(acc[i][1]),
                      tanhf(acc[i][2]), tanhf(acc[i][3]) };
        *reinterpret_cast<float4*>(&out[(size_t)r * DD + c0]) = o4;
    }
}

extern "C" void kernel_launch(void* const* d_in, const int* in_sizes, int n_in,
                              void* d_out, int out_size, void* d_ws, size_t ws_size,
                              hipStream_t stream) {
    const float* x  = (const float*)d_in[0];
    const float* W  = (const float*)d_in[1];
    const float* ew = (const float*)d_in[2];
    const int*   ei = (const int*)d_in[3];
    const int* rows = ei;
    const int* cols = ei + NE;
    float* out = (float*)d_out;               // final f32 output
    unsigned* aggp = (unsigned*)d_out;        // packed (hi,lo) agg lives here too

    // Workspace: hist[NB] | bin_off[NB] | bin_cursor[NB] | node_off[NN] |
    //            node_cnt[NN] | pad | bucket[NE] (uint2)
    size_t ints = (size_t)3 * NB + (size_t)2 * NN;
    size_t hdr = (ints + 3) & ~(size_t)3;
    size_t need = hdr * sizeof(int) + (size_t)NE * sizeof(uint2);

    if (ws_size >= need) {
        int* hist       = (int*)d_ws;
        int* bin_off    = hist + NB;
        int* bin_cursor = bin_off + NB;
        int* node_off   = bin_cursor + NB;
        int* node_cnt   = node_off + NN;
        uint2* bucket   = (uint2*)((int*)d_ws + hdr);

        hipMemsetAsync(hist, 0, (size_t)NB * sizeof(int), stream);
        hist_k<<<NE / T3, 256, 0, stream>>>(rows, hist);
        scan_k<<<1, 1024, 0, stream>>>(hist, bin_off, bin_cursor);
        tile_scatter_k<<<NE / T3, 256, 0, stream>>>(rows, cols, ew, bin_cursor, bucket);
        sort_bin_k<<<NB, 256, 0, stream>>>(bin_off, hist, bucket, node_off, node_cnt);
        gather_k<<<NN / 4, 256, 0, stream>>>(x, bucket, node_off, node_cnt, aggp);
        gemm_mfma_k<<<NB, 256, 0, stream>>>(aggp, W, out);
    } else {
        hipMemsetAsync(out, 0, (size_t)NN * DD * sizeof(float), stream);
        scatter_k<<<NE / 4, 256, 0, stream>>>(x, ew, rows, cols, out);
        gemm_tanh_k<<<NN / 32, 256, 0, stream>>>(out, W, out);
    }
}

// Round 7
// 293.567 us; speedup vs baseline: 12.2541x; 1.2445x over previous
//
#include <hip/hip_runtime.h>
#include <hip/hip_fp16.h>
#include <cstdint>

#define NN 100000
#define NE 3200000
#define DD 128

#define NB 782      // ceil(NN/128) node bins (128 nodes each)
#define NBP 800     // padded bin count for LDS arrays
#define T3 6400     // edges per tile (NE/T3 = 500 tiles)
#define EPT 25      // edges per thread (6400/256)

#define CAP 5120    // max records per bin in sort_bin_k (mean 4092, ~16 sigma)
#define RPT 20      // CAP/256

typedef __attribute__((ext_vector_type(8))) short s8v;   // 8 bf16 (4 VGPR)
typedef __attribute__((ext_vector_type(4))) float f4v;   // 4 f32 acc

__device__ __forceinline__ unsigned f2bf(float f) {       // RNE f32->bf16 bits
    unsigned u = __float_as_uint(f);
    return (u + 0x7fffu + ((u >> 16) & 1u)) >> 16;
}
__device__ __forceinline__ float bf2f(unsigned b) { return __uint_as_float(b << 16); }
__device__ __forceinline__ float tanh_fast(float x) {
    float e = __expf(2.0f * x);
    return 1.0f - 2.0f / (e + 1.0f);
}

// ---------------- K0: x f32 -> fp16 (RNE, |x|max ~5.5 << 65504) ----------
__global__ __launch_bounds__(256) void xcvt_k(
    const float* __restrict__ x, __half* __restrict__ xh)
{
    int i = (blockIdx.x * 256 + threadIdx.x) * 4;   // NN*DD % 1024 == 0
    float4 v = *reinterpret_cast<const float4*>(x + i);
    __half2 a = __floats2half2_rn(v.x, v.y);
    __half2 b = __floats2half2_rn(v.z, v.w);
    uint2 o = { *reinterpret_cast<unsigned*>(&a), *reinterpret_cast<unsigned*>(&b) };
    *reinterpret_cast<uint2*>(xh + i) = o;
}

// ---------------- K1: bin histogram (LDS pre-aggregated) ----------------
__global__ __launch_bounds__(256) void hist_k(
    const int* __restrict__ rows, int* __restrict__ hist)
{
    __shared__ int lh[NBP];
    int t = threadIdx.x;
    for (int b = t; b < NBP; b += 256) lh[b] = 0;
    __syncthreads();
    int base = blockIdx.x * T3;
    #pragma unroll
    for (int i = 0; i < EPT; ++i)
        atomicAdd(&lh[rows[base + i * 256 + t] >> 7], 1);
    __syncthreads();
    for (int b = t; b < NB; b += 256) {
        int v = lh[b];
        if (v) atomicAdd(&hist[b], v);
    }
}

// ---------------- K2: exclusive scan over bins ----------------
__global__ __launch_bounds__(1024) void scan_k(
    const int* __restrict__ hist, int* __restrict__ bin_off,
    int* __restrict__ bin_cursor)
{
    __shared__ int sd[1024];
    int t = threadIdx.x;
    int v = (t < NB) ? hist[t] : 0;
    sd[t] = v; __syncthreads();
    for (int off = 1; off < 1024; off <<= 1) {
        int add = (t >= off) ? sd[t - off] : 0;
        __syncthreads();
        sd[t] += add;
        __syncthreads();
    }
    if (t < NB) {
        int excl = sd[t] - v;
        bin_off[t] = excl;
        bin_cursor[t] = excl;
    }
}

// ---------------- K3: tile counting-sort scatter (validated r6) ----------
// Record: x = col | (r_local << 17), y = weight bits
__global__ __launch_bounds__(256) void tile_scatter_k(
    const int* __restrict__ rows, const int* __restrict__ cols,
    const float* __restrict__ ew, int* __restrict__ bin_cursor,
    uint2* __restrict__ bucket)
{
    __shared__ int h[NBP];
    __shared__ int toff[NBP];
    __shared__ int pos[NBP];
    __shared__ int gb[NBP];
    __shared__ int ps[256];
    __shared__ uint2 rec[T3];   // 50 KB

    int t = threadIdx.x;
    int base = blockIdx.x * T3;

    for (int b = t; b < NBP; b += 256) h[b] = 0;
    __syncthreads();

    int rv[EPT];
    #pragma unroll
    for (int i = 0; i < EPT; ++i) {
        int e = base + i * 256 + t;
        rv[i] = rows[e];
        atomicAdd(&h[rv[i] >> 7], 1);
    }
    __syncthreads();

    int c[4]; int s0 = 0;
    #pragma unroll
    for (int j = 0; j < 4; ++j) {
        int b = 4 * t + j;
        c[j] = (b < NBP) ? h[b] : 0;
        s0 += c[j];
    }
    ps[t] = s0; __syncthreads();
    for (int off = 1; off < 256; off <<= 1) {
        int add = (t >= off) ? ps[t - off] : 0;
        __syncthreads();
        ps[t] += add;
        __syncthreads();
    }
    int excl = ps[t] - s0;
    #pragma unroll
    for (int j = 0; j < 4; ++j) {
        int b = 4 * t + j;
        if (b < NBP) { toff[b] = excl; pos[b] = excl; excl += c[j]; }
    }
    __syncthreads();

    for (int b = t; b < NB; b += 256)
        gb[b] = atomicAdd(&bin_cursor[b], h[b]);
    __syncthreads();

    #pragma unroll
    for (int i = 0; i < EPT; ++i) {
        int e = base + i * 256 + t;
        int r = rv[i];
        int b = r >> 7;
        int slot = atomicAdd(&pos[b], 1);
        uint2 rr;
        rr.x = (unsigned)cols[e] | ((unsigned)(r & 127) << 17);
        rr.y = __float_as_uint(ew[e]);
        rec[slot] = rr;
    }
    __syncthreads();

    // all-lane flattened copy-out: thread t owns rec[EPT*t .. EPT*t+EPT)
    {
        int idx = EPT * t;
        int end_i = idx + EPT;
        int lo = 0, hi = NB - 1;          // largest b with toff[b] <= idx
        while (lo < hi) {
            int mid = (lo + hi + 1) >> 1;
            if (toff[mid] <= idx) lo = mid; else hi = mid - 1;
        }
        int b2 = lo;
        for (; idx < end_i; ++idx) {
            while (idx >= toff[b2] + h[b2]) ++b2;
            bucket[gb[b2] + (idx - toff[b2])] = rec[idx];
        }
    }
}

// ---------------- K4: per-bin node-granular counting sort (validated r6) -
__global__ __launch_bounds__(256) void sort_bin_k(
    const int* __restrict__ bin_off, const int* __restrict__ hist,
    uint2* __restrict__ bucket,
    int* __restrict__ node_off, int* __restrict__ node_cnt)
{
    __shared__ uint2 rec[CAP];      // 40 KB
    __shared__ int lh[128], sc[128], lpos[128];

    int b = blockIdx.x, t = threadIdx.x;
    int start = bin_off[b];
    int cnt = hist[b];
    if (cnt > CAP) cnt = CAP;

    uint2 mr[RPT];
    #pragma unroll
    for (int j = 0; j < RPT; ++j) {
        int idx = t + j * 256;
        mr[j] = (idx < cnt) ? bucket[start + idx] : make_uint2(0u, 0u);
    }

    if (t < 128) lh[t] = 0;
    __syncthreads();
    #pragma unroll
    for (int j = 0; j < RPT; ++j) {
        int idx = t + j * 256;
        if (idx < cnt) atomicAdd(&lh[(mr[j].x >> 17) & 127], 1);
    }
    __syncthreads();

    int v = (t < 128) ? lh[t] : 0;
    if (t < 128) sc[t] = v;
    __syncthreads();
    for (int off = 1; off < 128; off <<= 1) {
        int add = (t >= off && t < 128) ? sc[t - off] : 0;
        __syncthreads();
        if (t < 128) sc[t] += add;
        __syncthreads();
    }
    if (t < 128) {
        int excl = sc[t] - v;
        lpos[t] = excl;
        int node = b * 128 + t;
        if (node < NN) {
            node_off[node] = start + excl;
            node_cnt[node] = v;
        }
    }
    __syncthreads();

    #pragma unroll
    for (int j = 0; j < RPT; ++j) {
        int idx = t + j * 256;
        if (idx < cnt) {
            int slot = atomicAdd(&lpos[(mr[j].x >> 17) & 127], 1);
            rec[slot] = mr[j];
        }
    }
    __syncthreads();

    for (int i = t; i < cnt; i += 256)
        bucket[start + i] = rec[i];
}

// ---------------- K5: per-node gather from fp16 x, packed hi/lo out ------
__global__ __launch_bounds__(256) void gather_hf_k(
    const unsigned* __restrict__ xh,   // [NN][64] uints: 2 fp16/uint
    const uint2* __restrict__ bucket,
    const int* __restrict__ node_off, const int* __restrict__ node_cnt,
    unsigned* __restrict__ aggp)
{
    int node = blockIdx.x * 4 + (threadIdx.x >> 6);   // NN % 4 == 0
    int lane = threadIdx.x & 63;
    int start = node_off[node];
    int end   = start + node_cnt[node];

    float2 acc = {0.f, 0.f};
    int i = start;
    for (; i + 7 < end; i += 8) {
        uint2 e[8]; unsigned v[8];
        #pragma unroll
        for (int j = 0; j < 8; ++j) e[j] = bucket[i + j];
        #pragma unroll
        for (int j = 0; j < 8; ++j)
            v[j] = xh[(size_t)(e[j].x & 0x1FFFF) * 64 + lane];
        #pragma unroll
        for (int j = 0; j < 8; ++j) {
            float w = __uint_as_float(e[j].y);
            __half2 h2 = *reinterpret_cast<__half2*>(&v[j]);
            float2 f2 = __half22float2(h2);
            acc.x += w * f2.x;
            acc.y += w * f2.y;
        }
    }
    for (; i < end; ++i) {
        uint2 e0 = bucket[i];
        unsigned v0 = xh[(size_t)(e0.x & 0x1FFFF) * 64 + lane];
        float w = __uint_as_float(e0.y);
        __half2 h2 = *reinterpret_cast<__half2*>(&v0);
        float2 f2 = __half22float2(h2);
        acc.x += w * f2.x;
        acc.y += w * f2.y;
    }

    unsigned hx = f2bf(acc.x);
    unsigned lx = f2bf(acc.x - bf2f(hx));
    unsigned hy = f2bf(acc.y);
    unsigned ly = f2bf(acc.y - bf2f(hy));
    uint2 o;
    o.x = (hx << 16) | lx;
    o.y = (hy << 16) | ly;
    reinterpret_cast<uint2*>(aggp + (size_t)node * DD)[lane] = o;
}

// ---------------- K5b: f32 gather (fallback if ws lacks xh space) --------
__global__ __launch_bounds__(256) void gather_k(
    const float* __restrict__ x, const uint2* __restrict__ bucket,
    const int* __restrict__ node_off, const int* __restrict__ node_cnt,
    unsigned* __restrict__ aggp)
{
    int node = blockIdx.x * 4 + (threadIdx.x >> 6);
    int lane = threadIdx.x & 63;
    int start = node_off[node];
    int end   = start + node_cnt[node];
    const float2* x2 = reinterpret_cast<const float2*>(x);

    float2 acc = {0.f, 0.f};
    int i = start;
    for (; i + 3 < end; i += 4) {
        uint2 e0 = bucket[i],     e1 = bucket[i + 1];
        uint2 e2 = bucket[i + 2], e3 = bucket[i + 3];
        float2 v0 = x2[(size_t)(e0.x & 0x1FFFF) * 64 + lane];
        float2 v1 = x2[(size_t)(e1.x & 0x1FFFF) * 64 + lane];
        float2 v2 = x2[(size_t)(e2.x & 0x1FFFF) * 64 + lane];
        float2 v3 = x2[(size_t)(e3.x & 0x1FFFF) * 64 + lane];
        float w0 = __uint_as_float(e0.y), w1 = __uint_as_float(e1.y);
        float w2 = __uint_as_float(e2.y), w3 = __uint_as_float(e3.y);
        acc.x += w0 * v0.x; acc.y += w0 * v0.y;
        acc.x += w1 * v1.x; acc.y += w1 * v1.y;
        acc.x += w2 * v2.x; acc.y += w2 * v2.y;
        acc.x += w3 * v3.x; acc.y += w3 * v3.y;
    }
    for (; i < end; ++i) {
        uint2 e0 = bucket[i];
        float2 v0 = x2[(size_t)(e0.x & 0x1FFFF) * 64 + lane];
        float w0 = __uint_as_float(e0.y);
        acc.x += w0 * v0.x; acc.y += w0 * v0.y;
    }

    unsigned hx = f2bf(acc.x);
    unsigned lx = f2bf(acc.x - bf2f(hx));
    unsigned hy = f2bf(acc.y);
    unsigned ly = f2bf(acc.y - bf2f(hy));
    uint2 o;
    o.x = (hx << 16) | lx;
    o.y = (hy << 16) | ly;
    reinterpret_cast<uint2*>(aggp + (size_t)node * DD)[lane] = o;
}

// ---------------- K6: MFMA GEMM + tanh (bf16 hi/lo split, validated r5) --
__device__ __forceinline__ int wswz(int o, int k) {
    int byte = (o << 8) + (k << 1);
    byte ^= (o & 7) << 4;
    return byte >> 1;
}
__device__ __forceinline__ void unpack8(uint4 a, uint4 b, s8v& hi, s8v& lo) {
    unsigned u[8] = {a.x, a.y, a.z, a.w, b.x, b.y, b.z, b.w};
    #pragma unroll
    for (int j = 0; j < 8; ++j) {
        hi[j] = (short)(u[j] >> 16);
        lo[j] = (short)(u[j] & 0xffffu);
    }
}

__global__ __launch_bounds__(256) void gemm_mfma_k(
    const unsigned* __restrict__ aggp, const float* __restrict__ W,
    float* __restrict__ out)
{
    __shared__ __align__(16) unsigned short Wh[128 * 128];  // 32 KB
    __shared__ __align__(16) unsigned short Wl[128 * 128];  // 32 KB

    int t = threadIdx.x;
    for (int i = t; i < 128 * 128; i += 256) {
        int o = i >> 7, k = i & 127;
        float f = W[i];
        unsigned h = f2bf(f);
        unsigned l = f2bf(f - bf2f(h));
        int idx = wswz(o, k);
        Wh[idx] = (unsigned short)h;
        Wl[idx] = (unsigned short)l;
    }
    __syncthreads();

    int lane = t & 63;
    int w    = t >> 6;
    int rbase = blockIdx.x * 128 + w * 32;
    int fr = lane & 15, fq = lane >> 4;

    f4v acc[2][8];
    #pragma unroll
    for (int rt = 0; rt < 2; ++rt)
        #pragma unroll
        for (int nt = 0; nt < 8; ++nt)
            acc[rt][nt] = 0.0f;

    #pragma unroll
    for (int ks = 0; ks < 4; ++ks) {
        int kb = ks * 32 + fq * 8;
        s8v ah[2], al[2];
        #pragma unroll
        for (int rt = 0; rt < 2; ++rt) {
            int r = rbase + rt * 16 + fr;
            int rc = (r < NN) ? r : (NN - 1);
            const uint4* p = reinterpret_cast<const uint4*>(aggp + (size_t)rc * DD + kb);
            unpack8(p[0], p[1], ah[rt], al[rt]);
        }
        #pragma unroll
        for (int nt = 0; nt < 8; ++nt) {
            int o = nt * 16 + fr;
            int kk = ks * 32 + fq * 8;
            s8v bh = *reinterpret_cast<const s8v*>(&Wh[wswz(o, kk)]);
            s8v bl = *reinterpret_cast<const s8v*>(&Wl[wswz(o, kk)]);
            #pragma unroll
            for (int rt = 0; rt < 2; ++rt) {
                acc[rt][nt] = __builtin_amdgcn_mfma_f32_16x16x32_bf16(ah[rt], bh, acc[rt][nt], 0, 0, 0);
                acc[rt][nt] = __builtin_amdgcn_mfma_f32_16x16x32_bf16(al[rt], bh, acc[rt][nt], 0, 0, 0);
                acc[rt][nt] = __builtin_amdgcn_mfma_f32_16x16x32_bf16(ah[rt], bl, acc[rt][nt], 0, 0, 0);
            }
        }
    }

    #pragma unroll
    for (int rt = 0; rt < 2; ++rt) {
        int rr = rbase + rt * 16 + fq * 4;
        #pragma unroll
        for (int nt = 0; nt < 8; ++nt) {
            int col = nt * 16 + fr;
            #pragma unroll
            for (int j = 0; j < 4; ++j) {
                int row = rr + j;
                if (row < NN)
                    out[(size_t)row * DD + col] = tanh_fast(acc[rt][nt][j]);
            }
        }
    }
}

// ---------------- deep fallback (ws too small for any bucket) ------------
__global__ __launch_bounds__(256) void scatter_k(
    const float* __restrict__ x, const float* __restrict__ ew,
    const int* __restrict__ rows, const int* __restrict__ cols,
    float* __restrict__ agg)
{
    int e    = blockIdx.x * 4 + (threadIdx.x >> 6);
    int lane = threadIdx.x & 63;
    int r = rows[e];
    int c = cols[e];
    float w = ew[e];
    float2 v = reinterpret_cast<const float2*>(x + (size_t)c * DD)[lane];
    float* ag = agg + (size_t)r * DD + lane * 2;
    atomicAdd(ag,     w * v.x);
    atomicAdd(ag + 1, w * v.y);
}

__global__ __launch_bounds__(256) void gemm_tanh_k(
    const float* __restrict__ agg, const float* __restrict__ W,
    float* __restrict__ out)
{
    __shared__ float Wt[DD][DD + 4];
    __shared__ float At[32][DD];

    int tid = threadIdx.x;
    for (int i = tid; i < DD * DD; i += 256) {
        int o = i >> 7, k = i & 127;
        Wt[k][o] = W[i];
    }
    int row0 = blockIdx.x * 32;
    for (int i = tid; i < 32 * DD; i += 256) {
        At[i >> 7][i & 127] = agg[(size_t)row0 * DD + i];
    }
    __syncthreads();

    int colg = tid & 31;
    int rowg = tid >> 5;
    int c0 = colg * 4;
    int r0 = rowg * 4;

    float acc[4][4] = {};
    for (int k = 0; k < DD; ++k) {
        float4 wv = *reinterpret_cast<const float4*>(&Wt[k][c0]);
        #pragma unroll
        for (int i = 0; i < 4; ++i) {
            float a = At[r0 + i][k];
            acc[i][0] += a * wv.x;
            acc[i][1] += a * wv.y;
            acc[i][2] += a * wv.z;
            acc[i][3] += a * wv.w;
        }
    }

    #pragma unroll
    for (int i = 0; i < 4; ++i) {
        int r = row0 + r0 + i;
        float4 o4 = { tanhf(acc[i][0]), tanhf(acc[i][1]),
                      tanhf(acc[i][2]), tanhf(acc[i][3]) };
        *reinterpret_cast<float4*>(&out[(size_t)r * DD + c0]) = o4;
    }
}

extern "C" void kernel_launch(void* const* d_in, const int* in_sizes, int n_in,
                              void* d_out, int out_size, void* d_ws, size_t ws_size,
                              hipStream_t stream) {
    const float* x  = (const float*)d_in[0];
    const float* W  = (const float*)d_in[1];
    const float* ew = (const float*)d_in[2];
    const int*   ei = (const int*)d_in[3];
    const int* rows = ei;
    const int* cols = ei + NE;
    float* out = (float*)d_out;
    unsigned* aggp = (unsigned*)d_out;

    // Workspace: hist[NB] | bin_off[NB] | bin_cursor[NB] | node_off[NN] |
    //            node_cnt[NN] | pad | bucket[NE] uint2 | xh[NN*DD] half
    size_t ints = (size_t)3 * NB + (size_t)2 * NN;
    size_t hdr = (ints + 3) & ~(size_t)3;
    size_t need_base = hdr * sizeof(int) + (size_t)NE * sizeof(uint2);
    size_t need_full = need_base + (size_t)NN * DD * sizeof(__half);

    if (ws_size >= need_base) {
        int* hist       = (int*)d_ws;
        int* bin_off    = hist + NB;
        int* bin_cursor = bin_off + NB;
        int* node_off   = bin_cursor + NB;
        int* node_cnt   = node_off + NN;
        uint2* bucket   = (uint2*)((int*)d_ws + hdr);
        __half* xh      = (__half*)(bucket + NE);

        bool use_hf = (ws_size >= need_full);

        hipMemsetAsync(hist, 0, (size_t)NB * sizeof(int), stream);
        if (use_hf)
            xcvt_k<<<NN * DD / 1024, 256, 0, stream>>>(x, xh);
        hist_k<<<NE / T3, 256, 0, stream>>>(rows, hist);
        scan_k<<<1, 1024, 0, stream>>>(hist, bin_off, bin_cursor);
        tile_scatter_k<<<NE / T3, 256, 0, stream>>>(rows, cols, ew, bin_cursor, bucket);
        sort_bin_k<<<NB, 256, 0, stream>>>(bin_off, hist, bucket, node_off, node_cnt);
        if (use_hf)
            gather_hf_k<<<NN / 4, 256, 0, stream>>>((const unsigned*)xh, bucket,
                                                    node_off, node_cnt, aggp);
        else
            gather_k<<<NN / 4, 256, 0, stream>>>(x, bucket, node_off, node_cnt, aggp);
        gemm_mfma_k<<<NB, 256, 0, stream>>>(aggp, W, out);
    } else {
        hipMemsetAsync(out, 0, (size_t)NN * DD * sizeof(float), stream);
        scatter_k<<<NE / 4, 256, 0, stream>>>(x, ew, rows, cols, out);
        gemm_tanh_k<<<NN / 32, 256, 0, stream>>>(out, W, out);
    }
}